// Round 5
// baseline (5818.122 us; speedup 1.0000x reference)
//
#include <hip/hip_runtime.h>

#define TT 2048
#define DD 8
#define HH 64

// LDS layout (floats):
//   xbuf  [16384] @ 0      — whole x sequence for this block's batch (64 KB)
//   g0act [256]   @ 16384
//   g1act [256]   @ 16640
//   h0p   [64]    @ 16896
//   h1p   [64]    @ 16960
// total 17024 floats = 68096 B -> 2 blocks/CU (136 KB < 160 KB)
#define LDS_FLOATS 17024
#define LDS_BYTES  (LDS_FLOATS * 4)

// Pin a value into a VGPR: the empty asm's output is opaque, so the compiler
// cannot re-materialize the original global load inside the loop (rounds 1-3
// failure: loop-invariant weight loads sunk into the loop -> per-step L1/L2
// re-reads). Zero instructions emitted.
#define PIN(v) asm("" : "+v"(v))

__device__ __forceinline__ float sigm(float x) { return 1.0f / (1.0f + __expf(-x)); }
__device__ __forceinline__ float tanh_fast(float x) { return 1.0f - 2.0f / (__expf(2.0f * x) + 1.0f); }

// X-macro over the 16 k-quads
#define QUADS(F, M) \
  F(M,0,1,2,3)     F(M,4,5,6,7)     F(M,8,9,10,11)   F(M,12,13,14,15) \
  F(M,16,17,18,19) F(M,20,21,22,23) F(M,24,25,26,27) F(M,28,29,30,31) \
  F(M,32,33,34,35) F(M,36,37,38,39) F(M,40,41,42,43) F(M,44,45,46,47) \
  F(M,48,49,50,51) F(M,52,53,54,55) F(M,56,57,58,59) F(M,60,61,62,63)

#define DECLQ(M,a,b,c,d) float M##_##a, M##_##b, M##_##c, M##_##d;
#define LOADQ(M,a,b,c,d) { const float4 q = *(const float4*)(M##_ptr + a); \
  M##_##a = q.x; M##_##b = q.y; M##_##c = q.z; M##_##d = q.w; \
  PIN(M##_##a); PIN(M##_##b); PIN(M##_##c); PIN(M##_##d); }

// k-quad of the fused matvec: h0/h1 quads via uniform-address ds_read_b128
// (broadcast, conflict-free); 3 streams x 2 interleaved accumulators keep
// FMA dependency chains 16 deep (hidden at 2 waves/SIMD).
#define KQ(M,a,b,c,d) { \
  const float4 hq0 = *(const float4*)(h0p + a); \
  const float4 hq1 = *(const float4*)(h1p + a); \
  s1a = fmaf(wih1_##a, hq0.x, s1a); s0a = fmaf(whh0_##a, hq0.x, s0a); sBa = fmaf(whh1_##a, hq1.x, sBa); \
  s1b = fmaf(wih1_##b, hq0.y, s1b); s0b = fmaf(whh0_##b, hq0.y, s0b); sBb = fmaf(whh1_##b, hq1.y, sBb); \
  s1a = fmaf(wih1_##c, hq0.z, s1a); s0a = fmaf(whh0_##c, hq0.z, s0a); sBa = fmaf(whh1_##c, hq1.z, sBa); \
  s1b = fmaf(wih1_##d, hq0.w, s1b); s0b = fmaf(whh0_##d, hq0.w, s0b); sBb = fmaf(whh1_##d, hq1.w, sBb); }

// One block per batch element (512 blocks, 2/CU). Thread g owns gate row g of
// both layers: 200 weights in PINNED named VGPRs. x lives in LDS (staged once,
// coalesced — kills the 34 GB/step-refetch that bound rounds 1-2). h state is
// broadcast via uniform ds_read_b128 from 64-float LDS arrays. 3 barriers/step,
// all LDS patterns <=2-way (free). Cell updates replicated per wave (ln=g&63).
__global__ void __launch_bounds__(256)
    __attribute__((amdgpu_waves_per_eu(2, 2)))
    lstm2_fused(
        const float* __restrict__ x,
        const float* __restrict__ w_ih0, const float* __restrict__ w_hh0,
        const float* __restrict__ b_ih0, const float* __restrict__ b_hh0,
        const float* __restrict__ w_ih1, const float* __restrict__ w_hh1,
        const float* __restrict__ b_ih1, const float* __restrict__ b_hh1,
        const float* __restrict__ w_out, const float* __restrict__ b_out,
        float* __restrict__ out)
{
  extern __shared__ float smem[];
  float* const xbuf  = smem;
  float* const g0act = smem + 16384;
  float* const g1act = smem + 16640;
  float* const h0p   = smem + 16896;
  float* const h1p   = smem + 16960;

  const int b  = blockIdx.x;
  const int g  = threadIdx.x;     // gate row 0..255
  const int ln = g & 63;          // state element this thread tracks
  const bool is_tanh = ((g >> 6) == 2);  // gate order i,f,g,o

  // ---- one-time: stage the whole x sequence into LDS, coalesced ----
  {
    const float4* xg = (const float4*)(x + (size_t)b * (TT * DD));
    float4* xs = (float4*)xbuf;
#pragma unroll
    for (int i = 0; i < 16; ++i) xs[g + 256 * i] = xg[g + 256 * i];
  }
  if (g < 64) { h0p[g] = 0.0f; h1p[g] = 0.0f; }

  // ---- one-time: 200 weights into pinned named VGPRs ----
  const float* whh0_ptr = w_hh0 + g * HH;
  const float* wih1_ptr = w_ih1 + g * HH;
  const float* whh1_ptr = w_hh1 + g * HH;
  QUADS(DECLQ, whh0) QUADS(DECLQ, wih1) QUADS(DECLQ, whh1)
  QUADS(LOADQ, whh0) QUADS(LOADQ, wih1) QUADS(LOADQ, whh1)
  float wx_0, wx_1, wx_2, wx_3, wx_4, wx_5, wx_6, wx_7;
  {
    const float4 q0 = *(const float4*)(w_ih0 + g * DD);
    const float4 q1 = *(const float4*)(w_ih0 + g * DD + 4);
    wx_0 = q0.x; wx_1 = q0.y; wx_2 = q0.z; wx_3 = q0.w;
    wx_4 = q1.x; wx_5 = q1.y; wx_6 = q1.z; wx_7 = q1.w;
    PIN(wx_0); PIN(wx_1); PIN(wx_2); PIN(wx_3);
    PIN(wx_4); PIN(wx_5); PIN(wx_6); PIN(wx_7);
  }
  const float bias0 = b_ih0[g] + b_hh0[g];
  const float bias1 = b_ih1[g] + b_hh1[g];

  float c0 = 0.0f, c1 = 0.0f, h1v = 0.0f;
  float acc0 = bias0;  // carried: bias0 + Whh0 . h0(t-1); h0(-1)=0

  __syncthreads();  // x staged, h0p/h1p init visible

  for (int t = 0; t < TT; ++t) {
    // ---- phase A: layer-0 preact += Wih0.x(t); activate; publish ----
    {
      const float4 xq0 = *(const float4*)(xbuf + t * 8);
      const float4 xq1 = *(const float4*)(xbuf + t * 8 + 4);
      float p0 = acc0;
      p0 = fmaf(wx_0, xq0.x, p0);
      p0 = fmaf(wx_1, xq0.y, p0);
      p0 = fmaf(wx_2, xq0.z, p0);
      p0 = fmaf(wx_3, xq0.w, p0);
      p0 = fmaf(wx_4, xq1.x, p0);
      p0 = fmaf(wx_5, xq1.y, p0);
      p0 = fmaf(wx_6, xq1.z, p0);
      p0 = fmaf(wx_7, xq1.w, p0);
      g0act[g] = is_tanh ? tanh_fast(p0) : sigm(p0);
    }
    __syncthreads();  // bar1

    // ---- phase B: layer-0 cell update (replicated per wave); publish h0 ----
    {
      const float gi = g0act[ln];
      const float gf = g0act[64 + ln];
      const float gc = g0act[128 + ln];
      const float go = g0act[192 + ln];
      c0 = fmaf(gf, c0, gi * gc);
      const float h0v = go * tanh_fast(c0);
      if (g < 64) h0p[g] = h0v;
    }
    __syncthreads();  // bar2: h0p(t) visible

    // ---- phase C: layer-1 preact (Wih1.h0 + Whh1.h1) + next-step Whh0.h0 ----
    float s1a = bias1, s1b = 0.0f;
    float s0a = bias0, s0b = 0.0f;
    float sBa = 0.0f,  sBb = 0.0f;
    QUADS(KQ, _)
    acc0 = s0a + s0b;
    {
      const float p1 = (s1a + s1b) + (sBa + sBb);
      g1act[g] = is_tanh ? tanh_fast(p1) : sigm(p1);
    }
    __syncthreads();  // bar3

    // ---- phase D: layer-1 cell update; publish h1 for next step ----
    {
      const float gi = g1act[ln];
      const float gf = g1act[64 + ln];
      const float gc = g1act[128 + ln];
      const float go = g1act[192 + ln];
      c1 = fmaf(gf, c1, gi * gc);
      h1v = go * tanh_fast(c1);
      if (g < 64) h1p[g] = h1v;
    }
    // (no barrier here: next bar1+bar2 protect h1p/g1act before reuse)
  }

  // ---- head: out[b] = dot(h1, w_out) + b_out (wave 0 has h1v for lane g) ----
  if (g < 64) {
    float v = h1v * w_out[g];
#pragma unroll
    for (int off = 32; off; off >>= 1) v += __shfl_down(v, off);
    if (g == 0) out[b] = v + b_out[0];
  }
}

extern "C" void kernel_launch(void* const* d_in, const int* in_sizes, int n_in,
                              void* d_out, int out_size, void* d_ws, size_t ws_size,
                              hipStream_t stream) {
  const float* x     = (const float*)d_in[0];
  const float* w_ih0 = (const float*)d_in[1];
  const float* w_hh0 = (const float*)d_in[2];
  const float* b_ih0 = (const float*)d_in[3];
  const float* b_hh0 = (const float*)d_in[4];
  const float* w_ih1 = (const float*)d_in[5];
  const float* w_hh1 = (const float*)d_in[6];
  const float* b_ih1 = (const float*)d_in[7];
  const float* b_hh1 = (const float*)d_in[8];
  const float* w_out = (const float*)d_in[9];
  const float* b_out = (const float*)d_in[10];
  float* out = (float*)d_out;

  (void)hipFuncSetAttribute((const void*)lstm2_fused,
                            hipFuncAttributeMaxDynamicSharedMemorySize, LDS_BYTES);

  lstm2_fused<<<dim3(512), dim3(256), LDS_BYTES, stream>>>(
      x, w_ih0, w_hh0, b_ih0, b_hh0,
      w_ih1, w_hh1, b_ih1, b_hh1,
      w_out, b_out, out);
}

// Round 6
// 3516.132 us; speedup vs baseline: 1.6547x; 1.6547x over previous
//
#include <hip/hip_runtime.h>

#define TT 2048
#define DD 8
#define HH 64

// ---- LDS layout (float offsets) ----
#define O_W1 0        // wih1L[k][g], k-major: 64*256  (64 KB)
#define O_W0 16384    // whh0L[k][g]            (64 KB)
#define O_P0 32768    // part0[s][batch][gate] : 2*2*256
#define O_P1 33792    // part1[s][batch][gate]
#define O_H0 34816    // h0 packed float2[64] = (A,B)
#define O_H1 34944    // h1 packed float2[64]
#define NLDS 35072
#define LDS_BYTES (NLDS * 4)

__device__ __forceinline__ float sigm(float x)  { return 1.0f / (1.0f + __expf(-x)); }
__device__ __forceinline__ float tanh_(float x) { return 1.0f - 2.0f / (__expf(2.0f * x) + 1.0f); }

// 32 named whh1 scalars (R4 proved named scalars reach VGPRs; arrays don't)
#define W11Q(F) F(0,1,2,3) F(4,5,6,7) F(8,9,10,11) F(12,13,14,15) \
                F(16,17,18,19) F(20,21,22,23) F(24,25,26,27) F(28,29,30,31)
#define DECL4(a,b,c,d) float w11_##a, w11_##b, w11_##c, w11_##d;
#define LOAD4(a,b,c,d) { const float4 q = *(const float4*)(w11p + a); \
  w11_##a = q.x; w11_##b = q.y; w11_##c = q.z; w11_##d = q.w; }

#define PAIRS(F) F(0,1) F(2,3) F(4,5) F(6,7) F(8,9) F(10,11) F(12,13) F(14,15) \
                 F(16,17) F(18,19) F(20,21) F(22,23) F(24,25) F(26,27) F(28,29) F(30,31)

// one k-pair of the fused matvecs. Weights: ds_read_b32, banks g%32 -> 2-way
// (free). h broadcasts: uniform-address b128 (free). 12 fma, 12 accum chains.
#define KP(a,b) { \
  const float4 hq0 = *(const float4*)(h0f + 2*(a)); \
  const float4 hq1 = *(const float4*)(h1f + 2*(a)); \
  const float wA0 = w1g[(a)*256], wB0 = w0g[(a)*256]; \
  const float wA1 = w1g[(b)*256], wB1 = w0g[(b)*256]; \
  a1x = fmaf(wA0, hq0.x, a1x); a1y = fmaf(wA0, hq0.y, a1y); \
  a0x = fmaf(wB0, hq0.x, a0x); a0y = fmaf(wB0, hq0.y, a0y); \
  aCx = fmaf(w11_##a, hq1.x, aCx); aCy = fmaf(w11_##a, hq1.y, aCy); \
  b1x = fmaf(wA1, hq0.z, b1x); b1y = fmaf(wA1, hq0.w, b1y); \
  b0x = fmaf(wB1, hq0.z, b0x); b0y = fmaf(wB1, hq0.w, b0y); \
  bCx = fmaf(w11_##b, hq1.z, bCx); bCy = fmaf(w11_##b, hq1.w, bCy); \
}

// 256 blocks (1/CU), 512 threads (2 waves/SIMD), 2 batches/block.
// Thread (s=tid>>8, g=tid&255) owns k-half [32s,32s+32) of gate row g.
// Per-thread demand ~80 VGPRs -> no spill under any allocator class
// (R1/2/5 failure: >128 demand -> 108/128-class + scratch thrash).
// wih1/whh0 in LDS k-major (conflict-free); whh1-half + wih0-half named.
// x read via wave-uniform s_load (no 17-34 GB refetch). Waves 0-1 run
// layer-0 cell updates, waves 2-3 layer-1. 3 barriers/step.
__global__ void __launch_bounds__(512) lstm2_fused(
    const float* __restrict__ x,
    const float* __restrict__ w_ih0, const float* __restrict__ w_hh0,
    const float* __restrict__ b_ih0, const float* __restrict__ b_hh0,
    const float* __restrict__ w_ih1, const float* __restrict__ w_hh1,
    const float* __restrict__ b_ih1, const float* __restrict__ b_hh1,
    const float* __restrict__ w_out, const float* __restrict__ b_out,
    float* __restrict__ out)
{
  extern __shared__ float smem[];
  float* const w1L = smem + O_W1;
  float* const w0L = smem + O_W0;
  float* const p0  = smem + O_P0;
  float* const p1  = smem + O_P1;
  float* const h0f = smem + O_H0;
  float* const h1f = smem + O_H1;

  const int bb  = blockIdx.x;
  const int tid = threadIdx.x;
  const int g   = tid & 255;
  const int s   = tid >> 8;
  const int kb  = s * 32;
  const int su4 = __builtin_amdgcn_readfirstlane(s * 4);  // wave-uniform

  // ---- one-time: stage wih1/whh0 into LDS k-major (coalesced global) ----
  for (int i = tid; i < 256 * 64; i += 512) {
    const int gate = i >> 6, k = i & 63;  // coalesced reads; LDS write conflicts one-time
    w1L[k * 256 + gate] = w_ih1[i];
    w0L[k * 256 + gate] = w_hh0[i];
  }
  if (tid < 128) h0f[tid] = 0.0f;
  else if (tid < 256) h1f[tid - 128] = 0.0f;

  // ---- one-time: named weights (whh1 k-half: 32; wih0 d-half: 4) ----
  const float* w11p = w_hh1 + g * HH + kb;
  W11Q(DECL4)
  W11Q(LOAD4)
  float wx0, wx1, wx2, wx3;
  {
    const float4 q = *(const float4*)(w_ih0 + g * DD + su4);
    wx0 = q.x; wx1 = q.y; wx2 = q.z; wx3 = q.w;
  }
  const float bias0 = (s == 0) ? (b_ih0[g] + b_hh0[g]) : 0.0f;
  const float bias1 = (s == 0) ? (b_ih1[g] + b_hh1[g]) : 0.0f;

  // cell state: waves 0-1 own layer-0 cells (batch=tid>>6), waves 2-3 layer-1
  float cst = 0.0f;
  const int cl = tid & 63;           // cell lane
  const int cb = (tid >> 6) & 1;     // cell batch select

  // carried layer-0 partial: (s==0 bias) + my k-half of Whh0.h0(t-1)
  float carA = bias0, carB = bias0;

  // x base pointers (wave-uniform address stream -> s_load)
  const float* xA = x + (size_t)(2 * bb) * (TT * DD) + su4;
  const float* xB = xA + TT * DD;
  float4 xqA = *(const float4*)(xA);
  float4 xqB = *(const float4*)(xB);

  const float* const w1g = w1L + kb * 256 + g;
  const float* const w0g = w0L + kb * 256 + g;

  __syncthreads();

  for (int t = 0; t < TT; ++t) {
    // ---- phase A: finish layer-0 partial with my 4 x-columns; publish ----
    {
      float pA = carA, pB = carB;
      pA = fmaf(wx0, xqA.x, pA); pB = fmaf(wx0, xqB.x, pB);
      pA = fmaf(wx1, xqA.y, pA); pB = fmaf(wx1, xqB.y, pB);
      pA = fmaf(wx2, xqA.z, pA); pB = fmaf(wx2, xqB.z, pB);
      pA = fmaf(wx3, xqA.w, pA); pB = fmaf(wx3, xqB.w, pB);
      p0[s * 512 + g]       = pA;
      p0[s * 512 + 256 + g] = pB;
    }
    __syncthreads();  // bar1

    // prefetch x(t+1) — consumed next iteration
    {
      const int tn = (t + 1 < TT) ? (t + 1) : (TT - 1);
      xqA = *(const float4*)(xA + tn * DD);
      xqB = *(const float4*)(xB + tn * DD);
    }

    // ---- phase B (waves 0-1): layer-0 cell for (cb, cl); publish h0 ----
    if (tid < 128) {
      const float pi = p0[cb * 256 + cl]       + p0[512 + cb * 256 + cl];
      const float pf = p0[cb * 256 + 64 + cl]  + p0[512 + cb * 256 + 64 + cl];
      const float pg = p0[cb * 256 + 128 + cl] + p0[512 + cb * 256 + 128 + cl];
      const float po = p0[cb * 256 + 192 + cl] + p0[512 + cb * 256 + 192 + cl];
      cst = fmaf(sigm(pf), cst, sigm(pi) * tanh_(pg));
      h0f[2 * cl + cb] = sigm(po) * tanh_(cst);
    }
    __syncthreads();  // bar2: h0(t) visible

    // ---- phase C: layer-1 partial + next-step layer-0 Whh0 partial ----
    {
      float a1x = bias1, a1y = bias1, b1x = 0.f, b1y = 0.f;
      float a0x = bias0, a0y = bias0, b0x = 0.f, b0y = 0.f;
      float aCx = 0.f, aCy = 0.f, bCx = 0.f, bCy = 0.f;
      const float* const h0k = h0f + 2 * kb;
      const float* const h1k = h1f + 2 * kb;
      {
        const float* h0f_ = h0k; const float* h1f_ = h1k;
        // rename for macro use
        #define h0f h0f_
        #define h1f h1f_
        PAIRS(KP)
        #undef h0f
        #undef h1f
      }
      p1[s * 512 + g]       = (a1x + b1x) + (aCx + bCx);
      p1[s * 512 + 256 + g] = (a1y + b1y) + (aCy + bCy);
      carA = a0x + b0x;
      carB = a0y + b0y;
    }
    __syncthreads();  // bar3

    // ---- phase D (waves 2-3): layer-1 cell; publish h1 for next step ----
    if (tid >= 128 && tid < 256) {
      const float pi = p1[cb * 256 + cl]       + p1[512 + cb * 256 + cl];
      const float pf = p1[cb * 256 + 64 + cl]  + p1[512 + cb * 256 + 64 + cl];
      const float pg = p1[cb * 256 + 128 + cl] + p1[512 + cb * 256 + 128 + cl];
      const float po = p1[cb * 256 + 192 + cl] + p1[512 + cb * 256 + 192 + cl];
      cst = fmaf(sigm(pf), cst, sigm(pi) * tanh_(pg));
      h1f[2 * cl + cb] = sigm(po) * tanh_(cst);
    }
    // no barrier: bar1+bar2 of next step order h1f before its phase-C readers
  }

  __syncthreads();  // final h1 visible

  // ---- head: out[b] = dot(h1, w_out) + b_out ----
  if (tid < 64) {
    const float wv = w_out[tid];
    float vA = h1f[2 * tid] * wv;
    float vB = h1f[2 * tid + 1] * wv;
#pragma unroll
    for (int off = 32; off; off >>= 1) {
      vA += __shfl_down(vA, off);
      vB += __shfl_down(vB, off);
    }
    if (tid == 0) {
      out[2 * bb]     = vA + b_out[0];
      out[2 * bb + 1] = vB + b_out[0];
    }
  }
}

extern "C" void kernel_launch(void* const* d_in, const int* in_sizes, int n_in,
                              void* d_out, int out_size, void* d_ws, size_t ws_size,
                              hipStream_t stream) {
  const float* x     = (const float*)d_in[0];
  const float* w_ih0 = (const float*)d_in[1];
  const float* w_hh0 = (const float*)d_in[2];
  const float* b_ih0 = (const float*)d_in[3];
  const float* b_hh0 = (const float*)d_in[4];
  const float* w_ih1 = (const float*)d_in[5];
  const float* w_hh1 = (const float*)d_in[6];
  const float* b_ih1 = (const float*)d_in[7];
  const float* b_hh1 = (const float*)d_in[8];
  const float* w_out = (const float*)d_in[9];
  const float* b_out = (const float*)d_in[10];
  float* out = (float*)d_out;

  (void)hipFuncSetAttribute((const void*)lstm2_fused,
                            hipFuncAttributeMaxDynamicSharedMemorySize, LDS_BYTES);

  lstm2_fused<<<dim3(256), dim3(512), LDS_BYTES, stream>>>(
      x, w_ih0, w_hh0, b_ih0, b_hh0,
      w_ih1, w_hh1, b_ih1, b_hh1,
      w_out, b_out, out);
}